// Round 10
// baseline (633.187 us; speedup 1.0000x reference)
//
#include <hip/hip_runtime.h>
#include <cstddef>
#include <math.h>

typedef float v4 __attribute__((ext_vector_type(4)));

#define IMG_H 800
#define IMG_W 1216
#define FH 25
#define FWW 38
#define NBOX 2000
#define NKEEP 8
#define D1 100352   /* 2048*49 */
#define K1 4096
#define NSLICE 16
#define DPS (D1/NSLICE)  /* 6272 */

__device__ inline v4 ldnt4(const float* p) {
    return __builtin_nontemporal_load((const v4*)p);
}

// ---------------------------------------------------------------------------
// Kernel 1: greedy NMS (exact replica of reference loop) + ROI quantization.
// ---------------------------------------------------------------------------
__global__ __launch_bounds__(256) void nms_sel_kernel(const float* __restrict__ rois,
                                                      const float* __restrict__ scores,
                                                      int* __restrict__ roi_out) {
    __shared__ float4 s_box[NBOX];
    __shared__ float  s_fg[NBOX];
    __shared__ float  red_v[256];
    __shared__ int    red_i[256];
    __shared__ int    s_sels[NKEEP];
    const int tid = threadIdx.x;

    for (int i = tid; i < NBOX; i += 256) {
        float x1 = rois[i*4+0], y1 = rois[i*4+1], x2 = rois[i*4+2], y2 = rois[i*4+3];
        s_box[i] = make_float4(x1, y1, x2, y2);
        bool valid = (x1 >= 0.f) && (y1 >= 0.f) && (x2 <= (float)IMG_W) && (y2 <= (float)IMG_H);
        s_fg[i] = valid ? scores[i*2+1] : -INFINITY;
    }
    __syncthreads();

    for (int it = 0; it < NKEEP; ++it) {
        float bv = -INFINITY; int bi = NBOX;
        for (int i = tid; i < NBOX; i += 256) {
            float v = s_fg[i];
            if (v > bv || (v == bv && i < bi)) { bv = v; bi = i; }
        }
        red_v[tid] = bv; red_i[tid] = bi;
        __syncthreads();
        for (int off = 128; off > 0; off >>= 1) {
            if (tid < off) {
                float v = red_v[tid+off]; int ii = red_i[tid+off];
                if (v > red_v[tid] || (v == red_v[tid] && ii < red_i[tid])) {
                    red_v[tid] = v; red_i[tid] = ii;
                }
            }
            __syncthreads();
        }
        int s = red_i[0];
        if (s >= NBOX) s = 0;
        if (tid == 0) s_sels[it] = s;

        float4 bs = s_box[s];
        float a1 = (bs.z - bs.x) * (bs.w - bs.y);
        for (int i = tid; i < NBOX; i += 256) {
            float4 b = s_box[i];
            float ix1 = fmaxf(bs.x, b.x), iy1 = fmaxf(bs.y, b.y);
            float ix2 = fminf(bs.z, b.z), iy2 = fminf(bs.w, b.w);
            float inter = fmaxf(ix2 - ix1, 0.f) * fmaxf(iy2 - iy1, 0.f);
            float a2 = (b.z - b.x) * (b.w - b.y);
            float iou = inter / (a1 + a2 - inter);
            if (!(iou <= 0.6f)) s_fg[i] = -INFINITY;
        }
        __syncthreads();
    }

    if (tid < NKEEP) {
        int s = s_sels[tid];
        float4 b = s_box[s];
        int x = (int)floorf(b.x / 32.0f + 0.5f);
        int y = (int)floorf(b.y / 32.0f + 0.5f);
        int w = (int)floorf(b.z / 32.0f + 1.0f);
        int h = (int)floorf(b.w / 32.0f + 1.0f);
        bool bad = (x < 0) || (x >= FWW) || (y < 0) || (y >= FH) ||
                   (w < 1) || (x + w > FWW) || (h < 1) || (y + h > FH);
        if (bad) { x = 0; y = 0; w = FWW; h = FH; }
        roi_out[tid*4+0] = x; roi_out[tid*4+1] = y;
        roi_out[tid*4+2] = w; roi_out[tid*4+3] = h;
    }
}

// ---------------------------------------------------------------------------
// Kernel 2: adaptive 7x7 max-pool. pooled flat: idx = r*D1 + c*49 + i*7 + j
// ---------------------------------------------------------------------------
__global__ __launch_bounds__(256) void roi_pool_kernel(const float* __restrict__ feat,
                                                       const int* __restrict__ roi_out,
                                                       float* __restrict__ pooled) {
    int idx = blockIdx.x * 256 + threadIdx.x;
    if (idx >= NKEEP * D1) return;
    int r    = idx / D1;
    int rem  = idx - r * D1;
    int c    = rem / 49;
    int cell = rem - c * 49;
    int i = cell / 7;
    int j = cell - i * 7;
    int x = roi_out[r*4+0], y = roi_out[r*4+1], w = roi_out[r*4+2], h = roi_out[r*4+3];
    int r0 = y + (i * h) / 7;
    int r1 = y + ((i + 1) * h + 6) / 7;
    int c0 = x + (j * w) / 7;
    int c1 = x + ((j + 1) * w + 6) / 7;
    const float* fc = feat + (size_t)c * (FH * FWW);
    float m = -INFINITY;
    for (int rr = r0; rr < r1; ++rr) {
        const float* fr = fc + rr * FWW;
        for (int cc2 = c0; cc2 < c1; ++cc2) m = fmaxf(m, fr[cc2]);
    }
    pooled[idx] = m;
}

// ---------------------------------------------------------------------------
// Kernel 3: o[n][k] = b[k]  (bias init; fc1 atomically accumulates on top)
// ---------------------------------------------------------------------------
__global__ __launch_bounds__(256) void init_bias8_kernel(const float* __restrict__ b,
                                                         float* __restrict__ o, int K) {
    int i = blockIdx.x * 256 + threadIdx.x;
    if (i < NKEEP * K) o[i] = b[i & (K - 1)];
}

// ---------------------------------------------------------------------------
// Kernel 4: FC1 — R9 (best known). nt w-loads, 1-deep register prefetch.
// ---------------------------------------------------------------------------
__global__ __launch_bounds__(256) void fc1_kernel(const float* __restrict__ w1,
                                                  const float* __restrict__ flat,
                                                  float* __restrict__ o1) {
    const int kb = blockIdx.x >> 4;       // 0..63
    const int ds = blockIdx.x & 15;       // 0..15
    const int tid = threadIdx.x;
    const int kq = tid >> 4;              // 0..15
    const int dl = tid & 15;              // 0..15
    const int k0 = kb * 64 + kq * 4;
    const int dbase = ds * DPS + dl * 4;

    const float* wp = w1 + (size_t)k0 * D1 + dbase;
    const float* fp = flat + dbase;

    float acc[4][8];
    #pragma unroll
    for (int a = 0; a < 4; ++a)
        #pragma unroll
        for (int n = 0; n < 8; ++n) acc[a][n] = 0.f;

    v4 wa[4];
    #pragma unroll
    for (int a = 0; a < 4; ++a) wa[a] = ldnt4(wp + (size_t)a * D1);

    for (int itn = 0; itn < DPS / 64; ++itn) {   // 98 iters of 64 cols
        const int off  = itn * 64;
        const int offn = (itn < DPS / 64 - 1) ? off + 64 : off;  // dummy last

        v4 fv[8];
        #pragma unroll
        for (int n = 0; n < 8; ++n) fv[n] = *(const v4*)(fp + (size_t)n * D1 + off);

        v4 wb[4];
        #pragma unroll
        for (int a = 0; a < 4; ++a) wb[a] = ldnt4(wp + (size_t)a * D1 + offn);

        #pragma unroll
        for (int n = 0; n < 8; ++n) {
            acc[0][n] += wa[0][0]*fv[n][0] + wa[0][1]*fv[n][1] + wa[0][2]*fv[n][2] + wa[0][3]*fv[n][3];
            acc[1][n] += wa[1][0]*fv[n][0] + wa[1][1]*fv[n][1] + wa[1][2]*fv[n][2] + wa[1][3]*fv[n][3];
            acc[2][n] += wa[2][0]*fv[n][0] + wa[2][1]*fv[n][1] + wa[2][2]*fv[n][2] + wa[2][3]*fv[n][3];
            acc[3][n] += wa[3][0]*fv[n][0] + wa[3][1]*fv[n][1] + wa[3][2]*fv[n][2] + wa[3][3]*fv[n][3];
        }

        #pragma unroll
        for (int a = 0; a < 4; ++a) wa[a] = wb[a];
    }

    #pragma unroll
    for (int a = 0; a < 4; ++a) {
        #pragma unroll
        for (int n = 0; n < 8; ++n) {
            float v = acc[a][n];
            v += __shfl_xor(v, 1);
            v += __shfl_xor(v, 2);
            v += __shfl_xor(v, 4);
            v += __shfl_xor(v, 8);
            if (dl == 0) atomicAdd(&o1[n * K1 + k0 + a], v);
        }
    }
}

// ---------------------------------------------------------------------------
// Kernel 4-CALIB: fc1's EXACT w-access pattern & grid, minus f-loads/FMAs.
// Measures the pure-stream time of this pattern; T_A = dur_total - 384us.
// v4 adds keep every load live; per-block sink writes (no atomics).
// ---------------------------------------------------------------------------
__global__ __launch_bounds__(256) void calib_a_kernel(const float* __restrict__ w1,
                                                      float* __restrict__ sink) {
    const int kb = blockIdx.x >> 4;
    const int ds = blockIdx.x & 15;
    const int tid = threadIdx.x;
    const int kq = tid >> 4;
    const int dl = tid & 15;
    const int k0 = kb * 64 + kq * 4;
    const int dbase = ds * DPS + dl * 4;
    const float* wp = w1 + (size_t)k0 * D1 + dbase;

    v4 acc[4];
    #pragma unroll
    for (int a = 0; a < 4; ++a) acc[a] = (v4){0.f, 0.f, 0.f, 0.f};

    v4 wa[4];
    #pragma unroll
    for (int a = 0; a < 4; ++a) wa[a] = ldnt4(wp + (size_t)a * D1);

    for (int itn = 0; itn < DPS / 64; ++itn) {
        const int off  = itn * 64;
        const int offn = (itn < DPS / 64 - 1) ? off + 64 : off;

        v4 wb[4];
        #pragma unroll
        for (int a = 0; a < 4; ++a) wb[a] = ldnt4(wp + (size_t)a * D1 + offn);

        #pragma unroll
        for (int a = 0; a < 4; ++a) acc[a] += wa[a];

        #pragma unroll
        for (int a = 0; a < 4; ++a) wa[a] = wb[a];
    }

    v4 s = acc[0] + acc[1] + acc[2] + acc[3];
    sink[blockIdx.x * 256 + tid] = s[0] + s[1] + s[2] + s[3];
}

// ---------------------------------------------------------------------------
// Kernel 5: FC2 (8x4096)@(4096x4096). One wave per output row; nt w-loads.
// ---------------------------------------------------------------------------
__global__ __launch_bounds__(256) void fc2_kernel(const float* __restrict__ w2,
                                                  const float* __restrict__ o1,
                                                  const float* __restrict__ b2,
                                                  float* __restrict__ o2) {
    int gw   = (blockIdx.x * 256 + threadIdx.x) >> 6;
    int lane = threadIdx.x & 63;
    if (gw >= K1) return;
    const float* wr = w2 + (size_t)gw * K1;
    const v4* fo = (const v4*)o1;
    float acc[8];
    #pragma unroll
    for (int n = 0; n < 8; ++n) acc[n] = 0.f;
    for (int itn = 0; itn < K1 / 256; ++itn) {   // 16
        v4 wv = ldnt4(wr + (itn * 64 + lane) * 4);
        #pragma unroll
        for (int n = 0; n < 8; ++n) {
            v4 f = fo[n * (K1/4) + itn * 64 + lane];
            acc[n] += wv[0]*f[0] + wv[1]*f[1] + wv[2]*f[2] + wv[3]*f[3];
        }
    }
    #pragma unroll
    for (int n = 0; n < 8; ++n) {
        float v = acc[n];
        #pragma unroll
        for (int m = 32; m >= 1; m >>= 1) v += __shfl_xor(v, m);
        if (lane == 0) o2[n * K1 + gw] = v + b2[gw];
    }
}

// ---------------------------------------------------------------------------
// Kernel 6: heads. k<81 -> wc/bc, else wl/bl. out (8,405) row-major.
// ---------------------------------------------------------------------------
__global__ __launch_bounds__(256) void fc3_kernel(const float* __restrict__ wc,
                                                  const float* __restrict__ bc,
                                                  const float* __restrict__ wl,
                                                  const float* __restrict__ bl,
                                                  const float* __restrict__ o2,
                                                  float* __restrict__ out) {
    int gw   = (blockIdx.x * 256 + threadIdx.x) >> 6;
    int lane = threadIdx.x & 63;
    if (gw >= 405) return;
    const float* wrow; float bias;
    if (gw < 81) { wrow = wc + (size_t)gw * K1;        bias = bc[gw]; }
    else         { wrow = wl + (size_t)(gw - 81) * K1; bias = bl[gw - 81]; }
    const v4* fo = (const v4*)o2;
    float acc[8];
    #pragma unroll
    for (int n = 0; n < 8; ++n) acc[n] = 0.f;
    for (int itn = 0; itn < K1 / 256; ++itn) {
        v4 wv = ldnt4(wrow + (itn * 64 + lane) * 4);
        #pragma unroll
        for (int n = 0; n < 8; ++n) {
            v4 f = fo[n * (K1/4) + itn * 64 + lane];
            acc[n] += wv[0]*f[0] + wv[1]*f[1] + wv[2]*f[2] + wv[3]*f[3];
        }
    }
    #pragma unroll
    for (int n = 0; n < 8; ++n) {
        float v = acc[n];
        #pragma unroll
        for (int m = 32; m >= 1; m >>= 1) v += __shfl_xor(v, m);
        if (lane == 0) out[n * 405 + gw] = v + bias;
    }
}

// ---------------------------------------------------------------------------
extern "C" void kernel_launch(void* const* d_in, const int* in_sizes, int n_in,
                              void* d_out, int out_size, void* d_ws, size_t ws_size,
                              hipStream_t stream) {
    const float* feat   = (const float*)d_in[0];
    const float* rois   = (const float*)d_in[1];
    const float* scores = (const float*)d_in[2];
    const float* w1     = (const float*)d_in[3];
    const float* b1     = (const float*)d_in[4];
    const float* w2     = (const float*)d_in[5];
    const float* b2     = (const float*)d_in[6];
    const float* wc     = (const float*)d_in[7];
    const float* bc     = (const float*)d_in[8];
    const float* wl     = (const float*)d_in[9];
    const float* bl     = (const float*)d_in[10];
    float* out = (float*)d_out;

    // workspace layout (floats): [0..255] roi ints, then pooled, o1, o2;
    // calib sink parked at +16MB (far past o2, inside the large d_ws)
    int*   roi_out = (int*)d_ws;
    float* pooled  = (float*)d_ws + 256;
    float* o1      = pooled + (size_t)NKEEP * D1;
    float* o2      = o1 + NKEEP * K1;
    float* sink    = (float*)d_ws + (size_t)(1 << 22);

    nms_sel_kernel<<<1, 256, 0, stream>>>(rois, scores, roi_out);
    roi_pool_kernel<<<(NKEEP * D1 + 255) / 256, 256, 0, stream>>>(feat, roi_out, pooled);
    init_bias8_kernel<<<(NKEEP * K1 + 255) / 256, 256, 0, stream>>>(b1, o1, K1);
    fc1_kernel<<<64 * NSLICE, 256, 0, stream>>>(w1, pooled, o1);
    fc2_kernel<<<K1 / 4, 256, 0, stream>>>(w2, o1, b2, o2);
    fc3_kernel<<<(405 * 64 + 255) / 256, 256, 0, stream>>>(wc, bc, wl, bl, o2, out);
    // diagnostic: pure w1 stream with fc1's exact pattern (T_A = total - 384us)
    calib_a_kernel<<<64 * NSLICE, 256, 0, stream>>>(w1, sink);
}

// Round 12
// 422.228 us; speedup vs baseline: 1.4996x; 1.4996x over previous
//
#include <hip/hip_runtime.h>
#include <cstddef>
#include <math.h>

typedef float v4 __attribute__((ext_vector_type(4)));

#define IMG_H 800
#define IMG_W 1216
#define FH 25
#define FWW 38
#define NBOX 2000
#define NKEEP 8
#define D1 100352   /* 2048*49 */
#define K1 4096
#define NSLICE 56
#define DPS 1792    /* D1/NSLICE */

__device__ inline v4 ldnt4(const float* p) {
    return __builtin_nontemporal_load((const v4*)p);
}

// ---------------------------------------------------------------------------
// Kernel 1: greedy NMS (exact replica of reference loop) + ROI quantization.
// ---------------------------------------------------------------------------
__global__ __launch_bounds__(256) void nms_sel_kernel(const float* __restrict__ rois,
                                                      const float* __restrict__ scores,
                                                      int* __restrict__ roi_out) {
    __shared__ float4 s_box[NBOX];
    __shared__ float  s_fg[NBOX];
    __shared__ float  red_v[256];
    __shared__ int    red_i[256];
    __shared__ int    s_sels[NKEEP];
    const int tid = threadIdx.x;

    for (int i = tid; i < NBOX; i += 256) {
        float x1 = rois[i*4+0], y1 = rois[i*4+1], x2 = rois[i*4+2], y2 = rois[i*4+3];
        s_box[i] = make_float4(x1, y1, x2, y2);
        bool valid = (x1 >= 0.f) && (y1 >= 0.f) && (x2 <= (float)IMG_W) && (y2 <= (float)IMG_H);
        s_fg[i] = valid ? scores[i*2+1] : -INFINITY;
    }
    __syncthreads();

    for (int it = 0; it < NKEEP; ++it) {
        float bv = -INFINITY; int bi = NBOX;
        for (int i = tid; i < NBOX; i += 256) {
            float v = s_fg[i];
            if (v > bv || (v == bv && i < bi)) { bv = v; bi = i; }
        }
        red_v[tid] = bv; red_i[tid] = bi;
        __syncthreads();
        for (int off = 128; off > 0; off >>= 1) {
            if (tid < off) {
                float v = red_v[tid+off]; int ii = red_i[tid+off];
                if (v > red_v[tid] || (v == red_v[tid] && ii < red_i[tid])) {
                    red_v[tid] = v; red_i[tid] = ii;
                }
            }
            __syncthreads();
        }
        int s = red_i[0];
        if (s >= NBOX) s = 0;
        if (tid == 0) s_sels[it] = s;

        float4 bs = s_box[s];
        float a1 = (bs.z - bs.x) * (bs.w - bs.y);
        for (int i = tid; i < NBOX; i += 256) {
            float4 b = s_box[i];
            float ix1 = fmaxf(bs.x, b.x), iy1 = fmaxf(bs.y, b.y);
            float ix2 = fminf(bs.z, b.z), iy2 = fminf(bs.w, b.w);
            float inter = fmaxf(ix2 - ix1, 0.f) * fmaxf(iy2 - iy1, 0.f);
            float a2 = (b.z - b.x) * (b.w - b.y);
            float iou = inter / (a1 + a2 - inter);
            if (!(iou <= 0.6f)) s_fg[i] = -INFINITY;
        }
        __syncthreads();
    }

    if (tid < NKEEP) {
        int s = s_sels[tid];
        float4 b = s_box[s];
        int x = (int)floorf(b.x / 32.0f + 0.5f);
        int y = (int)floorf(b.y / 32.0f + 0.5f);
        int w = (int)floorf(b.z / 32.0f + 1.0f);
        int h = (int)floorf(b.w / 32.0f + 1.0f);
        bool bad = (x < 0) || (x >= FWW) || (y < 0) || (y >= FH) ||
                   (w < 1) || (x + w > FWW) || (h < 1) || (y + h > FH);
        if (bad) { x = 0; y = 0; w = FWW; h = FH; }
        roi_out[tid*4+0] = x; roi_out[tid*4+1] = y;
        roi_out[tid*4+2] = w; roi_out[tid*4+3] = h;
    }
}

// ---------------------------------------------------------------------------
// Kernel 2: adaptive 7x7 max-pool. pooled flat: idx = r*D1 + c*49 + i*7 + j
// ---------------------------------------------------------------------------
__global__ __launch_bounds__(256) void roi_pool_kernel(const float* __restrict__ feat,
                                                       const int* __restrict__ roi_out,
                                                       float* __restrict__ pooled) {
    int idx = blockIdx.x * 256 + threadIdx.x;
    if (idx >= NKEEP * D1) return;
    int r    = idx / D1;
    int rem  = idx - r * D1;
    int c    = rem / 49;
    int cell = rem - c * 49;
    int i = cell / 7;
    int j = cell - i * 7;
    int x = roi_out[r*4+0], y = roi_out[r*4+1], w = roi_out[r*4+2], h = roi_out[r*4+3];
    int r0 = y + (i * h) / 7;
    int r1 = y + ((i + 1) * h + 6) / 7;
    int c0 = x + (j * w) / 7;
    int c1 = x + ((j + 1) * w + 6) / 7;
    const float* fc = feat + (size_t)c * (FH * FWW);
    float m = -INFINITY;
    for (int rr = r0; rr < r1; ++rr) {
        const float* fr = fc + rr * FWW;
        for (int cc2 = c0; cc2 < c1; ++cc2) m = fmaxf(m, fr[cc2]);
    }
    pooled[idx] = m;
}

// ---------------------------------------------------------------------------
// Kernel 3: o[n][k] = b[k]  (bias init; fc1 atomically accumulates on top)
// ---------------------------------------------------------------------------
__global__ __launch_bounds__(256) void init_bias8_kernel(const float* __restrict__ b,
                                                         float* __restrict__ o, int K) {
    int i = blockIdx.x * 256 + threadIdx.x;
    if (i < NKEEP * K) o[i] = b[i & (K - 1)];
}

// ---------------------------------------------------------------------------
// Kernel 4: FC1 — calib-clean VMEM path. Block stages its 8x1792 f-slice
// (57KB LDS) ONCE; main loop (28 iters) = 4 nt w-loads (2-deep prefetch)
// + 8 ds_read_b128 (lgkmcnt, off the vmcnt path) + 128 FMAs.
// Grid = 64 kb x 56 ds = 3584 blocks; 2 blocks/CU, 8 waves/CU,
// 64KB/CU HBM bytes in flight.
// ---------------------------------------------------------------------------
__global__ __launch_bounds__(256) void fc1_kernel(const float* __restrict__ w1,
                                                  const float* __restrict__ flat,
                                                  float* __restrict__ o1) {
    __shared__ float s_f[NKEEP][DPS];     // 57344 B

    const int bid = blockIdx.x;
    const int kb  = bid / NSLICE;         // 0..63
    const int ds  = bid - kb * NSLICE;    // 0..55
    const int tid = threadIdx.x;
    const int kq  = tid >> 4;             // 0..15
    const int dl  = tid & 15;             // 0..15
    const int k0  = kb * 64 + kq * 4;
    const int dbase = ds * DPS;

    // ---- stage f slice once (coalesced v4, regular loads -> L2-cached) ----
    for (int i = tid; i < (NKEEP * DPS) / 4; i += 256) {   // 14 iters
        int n  = i / (DPS / 4);           // 0..7
        int c4 = i - n * (DPS / 4);
        *(v4*)&s_f[n][c4 * 4] = *(const v4*)(flat + (size_t)n * D1 + dbase + c4 * 4);
    }
    __syncthreads();

    const float* wp = w1 + (size_t)k0 * D1 + dbase + dl * 4;

    float acc[4][8];
    #pragma unroll
    for (int a = 0; a < 4; ++a)
        #pragma unroll
        for (int n = 0; n < 8; ++n) acc[a][n] = 0.f;

    // ---- 2-deep w prefetch ----
    v4 wa[4], wb[4];
    #pragma unroll
    for (int a = 0; a < 4; ++a) wa[a] = ldnt4(wp + (size_t)a * D1);
    #pragma unroll
    for (int a = 0; a < 4; ++a) wb[a] = ldnt4(wp + (size_t)a * D1 + 64);

    for (int itn = 0; itn < DPS / 64; ++itn) {   // 28 iters of 64 cols
        const int off  = itn * 64;
        const int offp = (itn < DPS / 64 - 2) ? off + 128 : 0;  // dummy tail

        // f from LDS (lgkmcnt path; 2-way bank alias = free)
        v4 fv[8];
        #pragma unroll
        for (int n = 0; n < 8; ++n) fv[n] = *(const v4*)&s_f[n][dl * 4 + off];

        // prefetch w tile itn+2 (nt, stays in flight through 2 FMA blocks)
        v4 wc_[4];
        #pragma unroll
        for (int a = 0; a < 4; ++a) wc_[a] = ldnt4(wp + (size_t)a * D1 + offp);

        #pragma unroll
        for (int n = 0; n < 8; ++n) {
            acc[0][n] += wa[0][0]*fv[n][0] + wa[0][1]*fv[n][1] + wa[0][2]*fv[n][2] + wa[0][3]*fv[n][3];
            acc[1][n] += wa[1][0]*fv[n][0] + wa[1][1]*fv[n][1] + wa[1][2]*fv[n][2] + wa[1][3]*fv[n][3];
            acc[2][n] += wa[2][0]*fv[n][0] + wa[2][1]*fv[n][1] + wa[2][2]*fv[n][2] + wa[2][3]*fv[n][3];
            acc[3][n] += wa[3][0]*fv[n][0] + wa[3][1]*fv[n][1] + wa[3][2]*fv[n][2] + wa[3][3]*fv[n][3];
        }

        #pragma unroll
        for (int a = 0; a < 4; ++a) { wa[a] = wb[a]; wb[a] = wc_[a]; }
    }

    // reduce across the 16 dl-lanes, then atomic into o1
    #pragma unroll
    for (int a = 0; a < 4; ++a) {
        #pragma unroll
        for (int n = 0; n < 8; ++n) {
            float v = acc[a][n];
            v += __shfl_xor(v, 1);
            v += __shfl_xor(v, 2);
            v += __shfl_xor(v, 4);
            v += __shfl_xor(v, 8);
            if (dl == 0) atomicAdd(&o1[n * K1 + k0 + a], v);
        }
    }
}

// ---------------------------------------------------------------------------
// Kernel 5: FC2 (8x4096)@(4096x4096). One wave per output row; nt w-loads.
// ---------------------------------------------------------------------------
__global__ __launch_bounds__(256) void fc2_kernel(const float* __restrict__ w2,
                                                  const float* __restrict__ o1,
                                                  const float* __restrict__ b2,
                                                  float* __restrict__ o2) {
    int gw   = (blockIdx.x * 256 + threadIdx.x) >> 6;
    int lane = threadIdx.x & 63;
    if (gw >= K1) return;
    const float* wr = w2 + (size_t)gw * K1;
    const v4* fo = (const v4*)o1;
    float acc[8];
    #pragma unroll
    for (int n = 0; n < 8; ++n) acc[n] = 0.f;
    for (int itn = 0; itn < K1 / 256; ++itn) {   // 16
        v4 wv = ldnt4(wr + (itn * 64 + lane) * 4);
        #pragma unroll
        for (int n = 0; n < 8; ++n) {
            v4 f = fo[n * (K1/4) + itn * 64 + lane];
            acc[n] += wv[0]*f[0] + wv[1]*f[1] + wv[2]*f[2] + wv[3]*f[3];
        }
    }
    #pragma unroll
    for (int n = 0; n < 8; ++n) {
        float v = acc[n];
        #pragma unroll
        for (int m = 32; m >= 1; m >>= 1) v += __shfl_xor(v, m);
        if (lane == 0) o2[n * K1 + gw] = v + b2[gw];
    }
}

// ---------------------------------------------------------------------------
// Kernel 6: heads. k<81 -> wc/bc, else wl/bl. out (8,405) row-major.
// ---------------------------------------------------------------------------
__global__ __launch_bounds__(256) void fc3_kernel(const float* __restrict__ wc,
                                                  const float* __restrict__ bc,
                                                  const float* __restrict__ wl,
                                                  const float* __restrict__ bl,
                                                  const float* __restrict__ o2,
                                                  float* __restrict__ out) {
    int gw   = (blockIdx.x * 256 + threadIdx.x) >> 6;
    int lane = threadIdx.x & 63;
    if (gw >= 405) return;
    const float* wrow; float bias;
    if (gw < 81) { wrow = wc + (size_t)gw * K1;        bias = bc[gw]; }
    else         { wrow = wl + (size_t)(gw - 81) * K1; bias = bl[gw - 81]; }
    const v4* fo = (const v4*)o2;
    float acc[8];
    #pragma unroll
    for (int n = 0; n < 8; ++n) acc[n] = 0.f;
    for (int itn = 0; itn < K1 / 256; ++itn) {
        v4 wv = ldnt4(wrow + (itn * 64 + lane) * 4);
        #pragma unroll
        for (int n = 0; n < 8; ++n) {
            v4 f = fo[n * (K1/4) + itn * 64 + lane];
            acc[n] += wv[0]*f[0] + wv[1]*f[1] + wv[2]*f[2] + wv[3]*f[3];
        }
    }
    #pragma unroll
    for (int n = 0; n < 8; ++n) {
        float v = acc[n];
        #pragma unroll
        for (int m = 32; m >= 1; m >>= 1) v += __shfl_xor(v, m);
        if (lane == 0) out[n * 405 + gw] = v + bias;
    }
}

// ---------------------------------------------------------------------------
extern "C" void kernel_launch(void* const* d_in, const int* in_sizes, int n_in,
                              void* d_out, int out_size, void* d_ws, size_t ws_size,
                              hipStream_t stream) {
    const float* feat   = (const float*)d_in[0];
    const float* rois   = (const float*)d_in[1];
    const float* scores = (const float*)d_in[2];
    const float* w1     = (const float*)d_in[3];
    const float* b1     = (const float*)d_in[4];
    const float* w2     = (const float*)d_in[5];
    const float* b2     = (const float*)d_in[6];
    const float* wc     = (const float*)d_in[7];
    const float* bc     = (const float*)d_in[8];
    const float* wl     = (const float*)d_in[9];
    const float* bl     = (const float*)d_in[10];
    float* out = (float*)d_out;

    // workspace layout (floats): [0..255] roi ints, then pooled, o1, o2
    int*   roi_out = (int*)d_ws;
    float* pooled  = (float*)d_ws + 256;
    float* o1      = pooled + (size_t)NKEEP * D1;
    float* o2      = o1 + NKEEP * K1;

    nms_sel_kernel<<<1, 256, 0, stream>>>(rois, scores, roi_out);
    roi_pool_kernel<<<(NKEEP * D1 + 255) / 256, 256, 0, stream>>>(feat, roi_out, pooled);
    init_bias8_kernel<<<(NKEEP * K1 + 255) / 256, 256, 0, stream>>>(b1, o1, K1);
    fc1_kernel<<<64 * NSLICE, 256, 0, stream>>>(w1, pooled, o1);
    fc2_kernel<<<K1 / 4, 256, 0, stream>>>(w2, o1, b2, o2);
    fc3_kernel<<<(405 * 64 + 255) / 256, 256, 0, stream>>>(wc, bc, wl, bl, o2, out);
}

// Round 13
// 391.198 us; speedup vs baseline: 1.6186x; 1.0793x over previous
//
#include <hip/hip_runtime.h>
#include <cstddef>
#include <math.h>

typedef float v4 __attribute__((ext_vector_type(4)));

#define IMG_H 800
#define IMG_W 1216
#define FH 25
#define FWW 38
#define NBOX 2000
#define NKEEP 8
#define D1 100352   /* 2048*49 */
#define K1 4096
#define NSLICE 16
#define DPS (D1/NSLICE)  /* 6272 */

__device__ inline v4 ldnt4(const float* p) {
    return __builtin_nontemporal_load((const v4*)p);
}

// ---------------------------------------------------------------------------
// Kernel 1: greedy NMS (exact replica of reference loop) + ROI quantization.
// ---------------------------------------------------------------------------
__global__ __launch_bounds__(256) void nms_sel_kernel(const float* __restrict__ rois,
                                                      const float* __restrict__ scores,
                                                      int* __restrict__ roi_out) {
    __shared__ float4 s_box[NBOX];
    __shared__ float  s_fg[NBOX];
    __shared__ float  red_v[256];
    __shared__ int    red_i[256];
    __shared__ int    s_sels[NKEEP];
    const int tid = threadIdx.x;

    for (int i = tid; i < NBOX; i += 256) {
        float x1 = rois[i*4+0], y1 = rois[i*4+1], x2 = rois[i*4+2], y2 = rois[i*4+3];
        s_box[i] = make_float4(x1, y1, x2, y2);
        bool valid = (x1 >= 0.f) && (y1 >= 0.f) && (x2 <= (float)IMG_W) && (y2 <= (float)IMG_H);
        s_fg[i] = valid ? scores[i*2+1] : -INFINITY;
    }
    __syncthreads();

    for (int it = 0; it < NKEEP; ++it) {
        float bv = -INFINITY; int bi = NBOX;
        for (int i = tid; i < NBOX; i += 256) {
            float v = s_fg[i];
            if (v > bv || (v == bv && i < bi)) { bv = v; bi = i; }
        }
        red_v[tid] = bv; red_i[tid] = bi;
        __syncthreads();
        for (int off = 128; off > 0; off >>= 1) {
            if (tid < off) {
                float v = red_v[tid+off]; int ii = red_i[tid+off];
                if (v > red_v[tid] || (v == red_v[tid] && ii < red_i[tid])) {
                    red_v[tid] = v; red_i[tid] = ii;
                }
            }
            __syncthreads();
        }
        int s = red_i[0];
        if (s >= NBOX) s = 0;
        if (tid == 0) s_sels[it] = s;

        float4 bs = s_box[s];
        float a1 = (bs.z - bs.x) * (bs.w - bs.y);
        for (int i = tid; i < NBOX; i += 256) {
            float4 b = s_box[i];
            float ix1 = fmaxf(bs.x, b.x), iy1 = fmaxf(bs.y, b.y);
            float ix2 = fminf(bs.z, b.z), iy2 = fminf(bs.w, b.w);
            float inter = fmaxf(ix2 - ix1, 0.f) * fmaxf(iy2 - iy1, 0.f);
            float a2 = (b.z - b.x) * (b.w - b.y);
            float iou = inter / (a1 + a2 - inter);
            if (!(iou <= 0.6f)) s_fg[i] = -INFINITY;
        }
        __syncthreads();
    }

    if (tid < NKEEP) {
        int s = s_sels[tid];
        float4 b = s_box[s];
        int x = (int)floorf(b.x / 32.0f + 0.5f);
        int y = (int)floorf(b.y / 32.0f + 0.5f);
        int w = (int)floorf(b.z / 32.0f + 1.0f);
        int h = (int)floorf(b.w / 32.0f + 1.0f);
        bool bad = (x < 0) || (x >= FWW) || (y < 0) || (y >= FH) ||
                   (w < 1) || (x + w > FWW) || (h < 1) || (y + h > FH);
        if (bad) { x = 0; y = 0; w = FWW; h = FH; }
        roi_out[tid*4+0] = x; roi_out[tid*4+1] = y;
        roi_out[tid*4+2] = w; roi_out[tid*4+3] = h;
    }
}

// ---------------------------------------------------------------------------
// Kernel 2: adaptive 7x7 max-pool. pooled flat: idx = r*D1 + c*49 + i*7 + j
// ---------------------------------------------------------------------------
__global__ __launch_bounds__(256) void roi_pool_kernel(const float* __restrict__ feat,
                                                       const int* __restrict__ roi_out,
                                                       float* __restrict__ pooled) {
    int idx = blockIdx.x * 256 + threadIdx.x;
    if (idx >= NKEEP * D1) return;
    int r    = idx / D1;
    int rem  = idx - r * D1;
    int c    = rem / 49;
    int cell = rem - c * 49;
    int i = cell / 7;
    int j = cell - i * 7;
    int x = roi_out[r*4+0], y = roi_out[r*4+1], w = roi_out[r*4+2], h = roi_out[r*4+3];
    int r0 = y + (i * h) / 7;
    int r1 = y + ((i + 1) * h + 6) / 7;
    int c0 = x + (j * w) / 7;
    int c1 = x + ((j + 1) * w + 6) / 7;
    const float* fc = feat + (size_t)c * (FH * FWW);
    float m = -INFINITY;
    for (int rr = r0; rr < r1; ++rr) {
        const float* fr = fc + rr * FWW;
        for (int cc2 = c0; cc2 < c1; ++cc2) m = fmaxf(m, fr[cc2]);
    }
    pooled[idx] = m;
}

// ---------------------------------------------------------------------------
// Kernel 3: o[n][k] = b[k]  (bias init; fc1 atomically accumulates on top)
// ---------------------------------------------------------------------------
__global__ __launch_bounds__(256) void init_bias8_kernel(const float* __restrict__ b,
                                                         float* __restrict__ o, int K) {
    int i = blockIdx.x * 256 + threadIdx.x;
    if (i < NKEEP * K) o[i] = b[i & (K - 1)];
}

// ---------------------------------------------------------------------------
// Kernel 4: FC1 — R9 + 2-deep w prefetch (the single new variable).
// w for iter i+2 is issued at iter i: 8KB/wave in flight through the FMA
// block (vs 4KB at 1-deep), issue->use distance ~2048cy > queue-inflated
// HBM latency. VGPR ~126, still 4 waves/SIMD (occupancy unchanged vs R9).
// ---------------------------------------------------------------------------
__global__ __launch_bounds__(256) void fc1_kernel(const float* __restrict__ w1,
                                                  const float* __restrict__ flat,
                                                  float* __restrict__ o1) {
    const int kb = blockIdx.x >> 4;       // 0..63
    const int ds = blockIdx.x & 15;       // 0..15
    const int tid = threadIdx.x;
    const int kq = tid >> 4;              // 0..15
    const int dl = tid & 15;              // 0..15
    const int k0 = kb * 64 + kq * 4;
    const int dbase = ds * DPS + dl * 4;

    const float* wp = w1 + (size_t)k0 * D1 + dbase;
    const float* fp = flat + dbase;

    float acc[4][8];
    #pragma unroll
    for (int a = 0; a < 4; ++a)
        #pragma unroll
        for (int n = 0; n < 8; ++n) acc[a][n] = 0.f;

    // 2-deep prefetch: wa = tile 0, wb = tile 1
    v4 wa[4], wb[4];
    #pragma unroll
    for (int a = 0; a < 4; ++a) wa[a] = ldnt4(wp + (size_t)a * D1);
    #pragma unroll
    for (int a = 0; a < 4; ++a) wb[a] = ldnt4(wp + (size_t)a * D1 + 64);

    for (int itn = 0; itn < DPS / 64; ++itn) {   // 98 iters of 64 cols
        const int off  = itn * 64;
        const int offp = (itn < DPS / 64 - 2) ? off + 128 : 0;  // dummy tail

        // (1) f loads — L2-resident
        v4 fv[8];
        #pragma unroll
        for (int n = 0; n < 8; ++n) fv[n] = *(const v4*)(fp + (size_t)n * D1 + off);

        // (2) prefetch w tile itn+2 — in flight across TWO FMA blocks
        v4 wc_[4];
        #pragma unroll
        for (int a = 0; a < 4; ++a) wc_[a] = ldnt4(wp + (size_t)a * D1 + offp);

        // (3) FMA on the tile loaded two iterations ago
        #pragma unroll
        for (int n = 0; n < 8; ++n) {
            acc[0][n] += wa[0][0]*fv[n][0] + wa[0][1]*fv[n][1] + wa[0][2]*fv[n][2] + wa[0][3]*fv[n][3];
            acc[1][n] += wa[1][0]*fv[n][0] + wa[1][1]*fv[n][1] + wa[1][2]*fv[n][2] + wa[1][3]*fv[n][3];
            acc[2][n] += wa[2][0]*fv[n][0] + wa[2][1]*fv[n][1] + wa[2][2]*fv[n][2] + wa[2][3]*fv[n][3];
            acc[3][n] += wa[3][0]*fv[n][0] + wa[3][1]*fv[n][1] + wa[3][2]*fv[n][2] + wa[3][3]*fv[n][3];
        }

        #pragma unroll
        for (int a = 0; a < 4; ++a) { wa[a] = wb[a]; wb[a] = wc_[a]; }
    }

    // reduce across the 16 d-lanes, then atomic into o1
    #pragma unroll
    for (int a = 0; a < 4; ++a) {
        #pragma unroll
        for (int n = 0; n < 8; ++n) {
            float v = acc[a][n];
            v += __shfl_xor(v, 1);
            v += __shfl_xor(v, 2);
            v += __shfl_xor(v, 4);
            v += __shfl_xor(v, 8);
            if (dl == 0) atomicAdd(&o1[n * K1 + k0 + a], v);
        }
    }
}

// ---------------------------------------------------------------------------
// Kernel 5: FC2 (8x4096)@(4096x4096). One wave per output row; nt w-loads.
// ---------------------------------------------------------------------------
__global__ __launch_bounds__(256) void fc2_kernel(const float* __restrict__ w2,
                                                  const float* __restrict__ o1,
                                                  const float* __restrict__ b2,
                                                  float* __restrict__ o2) {
    int gw   = (blockIdx.x * 256 + threadIdx.x) >> 6;
    int lane = threadIdx.x & 63;
    if (gw >= K1) return;
    const float* wr = w2 + (size_t)gw * K1;
    const v4* fo = (const v4*)o1;
    float acc[8];
    #pragma unroll
    for (int n = 0; n < 8; ++n) acc[n] = 0.f;
    for (int itn = 0; itn < K1 / 256; ++itn) {   // 16
        v4 wv = ldnt4(wr + (itn * 64 + lane) * 4);
        #pragma unroll
        for (int n = 0; n < 8; ++n) {
            v4 f = fo[n * (K1/4) + itn * 64 + lane];
            acc[n] += wv[0]*f[0] + wv[1]*f[1] + wv[2]*f[2] + wv[3]*f[3];
        }
    }
    #pragma unroll
    for (int n = 0; n < 8; ++n) {
        float v = acc[n];
        #pragma unroll
        for (int m = 32; m >= 1; m >>= 1) v += __shfl_xor(v, m);
        if (lane == 0) o2[n * K1 + gw] = v + b2[gw];
    }
}

// ---------------------------------------------------------------------------
// Kernel 6: heads. k<81 -> wc/bc, else wl/bl. out (8,405) row-major.
// ---------------------------------------------------------------------------
__global__ __launch_bounds__(256) void fc3_kernel(const float* __restrict__ wc,
                                                  const float* __restrict__ bc,
                                                  const float* __restrict__ wl,
                                                  const float* __restrict__ bl,
                                                  const float* __restrict__ o2,
                                                  float* __restrict__ out) {
    int gw   = (blockIdx.x * 256 + threadIdx.x) >> 6;
    int lane = threadIdx.x & 63;
    if (gw >= 405) return;
    const float* wrow; float bias;
    if (gw < 81) { wrow = wc + (size_t)gw * K1;        bias = bc[gw]; }
    else         { wrow = wl + (size_t)(gw - 81) * K1; bias = bl[gw - 81]; }
    const v4* fo = (const v4*)o2;
    float acc[8];
    #pragma unroll
    for (int n = 0; n < 8; ++n) acc[n] = 0.f;
    for (int itn = 0; itn < K1 / 256; ++itn) {
        v4 wv = ldnt4(wrow + (itn * 64 + lane) * 4);
        #pragma unroll
        for (int n = 0; n < 8; ++n) {
            v4 f = fo[n * (K1/4) + itn * 64 + lane];
            acc[n] += wv[0]*f[0] + wv[1]*f[1] + wv[2]*f[2] + wv[3]*f[3];
        }
    }
    #pragma unroll
    for (int n = 0; n < 8; ++n) {
        float v = acc[n];
        #pragma unroll
        for (int m = 32; m >= 1; m >>= 1) v += __shfl_xor(v, m);
        if (lane == 0) out[n * 405 + gw] = v + bias;
    }
}

// ---------------------------------------------------------------------------
extern "C" void kernel_launch(void* const* d_in, const int* in_sizes, int n_in,
                              void* d_out, int out_size, void* d_ws, size_t ws_size,
                              hipStream_t stream) {
    const float* feat   = (const float*)d_in[0];
    const float* rois   = (const float*)d_in[1];
    const float* scores = (const float*)d_in[2];
    const float* w1     = (const float*)d_in[3];
    const float* b1     = (const float*)d_in[4];
    const float* w2     = (const float*)d_in[5];
    const float* b2     = (const float*)d_in[6];
    const float* wc     = (const float*)d_in[7];
    const float* bc     = (const float*)d_in[8];
    const float* wl     = (const float*)d_in[9];
    const float* bl     = (const float*)d_in[10];
    float* out = (float*)d_out;

    // workspace layout (floats): [0..255] roi ints, then pooled, o1, o2
    int*   roi_out = (int*)d_ws;
    float* pooled  = (float*)d_ws + 256;
    float* o1      = pooled + (size_t)NKEEP * D1;
    float* o2      = o1 + NKEEP * K1;

    nms_sel_kernel<<<1, 256, 0, stream>>>(rois, scores, roi_out);
    roi_pool_kernel<<<(NKEEP * D1 + 255) / 256, 256, 0, stream>>>(feat, roi_out, pooled);
    init_bias8_kernel<<<(NKEEP * K1 + 255) / 256, 256, 0, stream>>>(b1, o1, K1);
    fc1_kernel<<<64 * NSLICE, 256, 0, stream>>>(w1, pooled, o1);
    fc2_kernel<<<K1 / 4, 256, 0, stream>>>(w2, o1, b2, o2);
    fc3_kernel<<<(405 * 64 + 255) / 256, 256, 0, stream>>>(wc, bc, wl, bl, o2, out);
}

// Round 14
// 387.779 us; speedup vs baseline: 1.6329x; 1.0088x over previous
//
#include <hip/hip_runtime.h>
#include <cstddef>
#include <math.h>

typedef float v4 __attribute__((ext_vector_type(4)));

#define IMG_H 800
#define IMG_W 1216
#define FH 25
#define FWW 38
#define NBOX 2000
#define NKEEP 8
#define D1 100352   /* 2048*49 */
#define K1 4096
#define NSLICE 16
#define DPS (D1/NSLICE)  /* 6272 */

__device__ inline v4 ldnt4(const float* p) {
    return __builtin_nontemporal_load((const v4*)p);
}

// ---------------------------------------------------------------------------
// Kernel 1: greedy NMS (exact replica of reference loop) + ROI quantization.
// ---------------------------------------------------------------------------
__global__ __launch_bounds__(256) void nms_sel_kernel(const float* __restrict__ rois,
                                                      const float* __restrict__ scores,
                                                      int* __restrict__ roi_out) {
    __shared__ float4 s_box[NBOX];
    __shared__ float  s_fg[NBOX];
    __shared__ float  red_v[256];
    __shared__ int    red_i[256];
    __shared__ int    s_sels[NKEEP];
    const int tid = threadIdx.x;

    for (int i = tid; i < NBOX; i += 256) {
        float x1 = rois[i*4+0], y1 = rois[i*4+1], x2 = rois[i*4+2], y2 = rois[i*4+3];
        s_box[i] = make_float4(x1, y1, x2, y2);
        bool valid = (x1 >= 0.f) && (y1 >= 0.f) && (x2 <= (float)IMG_W) && (y2 <= (float)IMG_H);
        s_fg[i] = valid ? scores[i*2+1] : -INFINITY;
    }
    __syncthreads();

    for (int it = 0; it < NKEEP; ++it) {
        float bv = -INFINITY; int bi = NBOX;
        for (int i = tid; i < NBOX; i += 256) {
            float v = s_fg[i];
            if (v > bv || (v == bv && i < bi)) { bv = v; bi = i; }
        }
        red_v[tid] = bv; red_i[tid] = bi;
        __syncthreads();
        for (int off = 128; off > 0; off >>= 1) {
            if (tid < off) {
                float v = red_v[tid+off]; int ii = red_i[tid+off];
                if (v > red_v[tid] || (v == red_v[tid] && ii < red_i[tid])) {
                    red_v[tid] = v; red_i[tid] = ii;
                }
            }
            __syncthreads();
        }
        int s = red_i[0];
        if (s >= NBOX) s = 0;
        if (tid == 0) s_sels[it] = s;

        float4 bs = s_box[s];
        float a1 = (bs.z - bs.x) * (bs.w - bs.y);
        for (int i = tid; i < NBOX; i += 256) {
            float4 b = s_box[i];
            float ix1 = fmaxf(bs.x, b.x), iy1 = fmaxf(bs.y, b.y);
            float ix2 = fminf(bs.z, b.z), iy2 = fminf(bs.w, b.w);
            float inter = fmaxf(ix2 - ix1, 0.f) * fmaxf(iy2 - iy1, 0.f);
            float a2 = (b.z - b.x) * (b.w - b.y);
            float iou = inter / (a1 + a2 - inter);
            if (!(iou <= 0.6f)) s_fg[i] = -INFINITY;
        }
        __syncthreads();
    }

    if (tid < NKEEP) {
        int s = s_sels[tid];
        float4 b = s_box[s];
        int x = (int)floorf(b.x / 32.0f + 0.5f);
        int y = (int)floorf(b.y / 32.0f + 0.5f);
        int w = (int)floorf(b.z / 32.0f + 1.0f);
        int h = (int)floorf(b.w / 32.0f + 1.0f);
        bool bad = (x < 0) || (x >= FWW) || (y < 0) || (y >= FH) ||
                   (w < 1) || (x + w > FWW) || (h < 1) || (y + h > FH);
        if (bad) { x = 0; y = 0; w = FWW; h = FH; }
        roi_out[tid*4+0] = x; roi_out[tid*4+1] = y;
        roi_out[tid*4+2] = w; roi_out[tid*4+3] = h;
    }
}

// ---------------------------------------------------------------------------
// Kernel 2: adaptive 7x7 max-pool. pooled flat: idx = r*D1 + c*49 + i*7 + j
// ---------------------------------------------------------------------------
__global__ __launch_bounds__(256) void roi_pool_kernel(const float* __restrict__ feat,
                                                       const int* __restrict__ roi_out,
                                                       float* __restrict__ pooled) {
    int idx = blockIdx.x * 256 + threadIdx.x;
    if (idx >= NKEEP * D1) return;
    int r    = idx / D1;
    int rem  = idx - r * D1;
    int c    = rem / 49;
    int cell = rem - c * 49;
    int i = cell / 7;
    int j = cell - i * 7;
    int x = roi_out[r*4+0], y = roi_out[r*4+1], w = roi_out[r*4+2], h = roi_out[r*4+3];
    int r0 = y + (i * h) / 7;
    int r1 = y + ((i + 1) * h + 6) / 7;
    int c0 = x + (j * w) / 7;
    int c1 = x + ((j + 1) * w + 6) / 7;
    const float* fc = feat + (size_t)c * (FH * FWW);
    float m = -INFINITY;
    for (int rr = r0; rr < r1; ++rr) {
        const float* fr = fc + rr * FWW;
        for (int cc2 = c0; cc2 < c1; ++cc2) m = fmaxf(m, fr[cc2]);
    }
    pooled[idx] = m;
}

// ---------------------------------------------------------------------------
// Kernel 3: o[n][k] = b[k]  (bias init; fc1 atomically accumulates on top)
// ---------------------------------------------------------------------------
__global__ __launch_bounds__(256) void init_bias8_kernel(const float* __restrict__ b,
                                                         float* __restrict__ o, int K) {
    int i = blockIdx.x * 256 + threadIdx.x;
    if (i < NKEEP * K) o[i] = b[i & (K - 1)];
}

// ---------------------------------------------------------------------------
// Kernel 4: FC1 — best known (R9): nt w-loads + 1-deep register prefetch.
// 4 rows x 8 ROIs per thread; f issued first (L2-fast), next iter's w
// prefetched before the FMA block. ~4.9 TB/s effective on the 1.64GB stream.
// ---------------------------------------------------------------------------
__global__ __launch_bounds__(256) void fc1_kernel(const float* __restrict__ w1,
                                                  const float* __restrict__ flat,
                                                  float* __restrict__ o1) {
    const int kb = blockIdx.x >> 4;       // 0..63
    const int ds = blockIdx.x & 15;       // 0..15
    const int tid = threadIdx.x;
    const int kq = tid >> 4;              // 0..15
    const int dl = tid & 15;              // 0..15
    const int k0 = kb * 64 + kq * 4;
    const int dbase = ds * DPS + dl * 4;

    const float* wp = w1 + (size_t)k0 * D1 + dbase;
    const float* fp = flat + dbase;

    float acc[4][8];
    #pragma unroll
    for (int a = 0; a < 4; ++a)
        #pragma unroll
        for (int n = 0; n < 8; ++n) acc[a][n] = 0.f;

    // preload iter-0 w (nontemporal)
    v4 wa[4];
    #pragma unroll
    for (int a = 0; a < 4; ++a) wa[a] = ldnt4(wp + (size_t)a * D1);

    for (int itn = 0; itn < DPS / 64; ++itn) {   // 98 iters of 64 cols
        const int off  = itn * 64;
        const int offn = (itn < DPS / 64 - 1) ? off + 64 : off;  // dummy last

        // (1) f loads — L2-resident, issued first so the FMA wait is cheap
        v4 fv[8];
        #pragma unroll
        for (int n = 0; n < 8; ++n) fv[n] = *(const v4*)(fp + (size_t)n * D1 + off);

        // (2) prefetch next iteration's w — nontemporal, stays in flight
        v4 wb[4];
        #pragma unroll
        for (int a = 0; a < 4; ++a) wb[a] = ldnt4(wp + (size_t)a * D1 + offn);

        // (3) FMA block on the w loaded one iteration ago
        #pragma unroll
        for (int n = 0; n < 8; ++n) {
            acc[0][n] += wa[0][0]*fv[n][0] + wa[0][1]*fv[n][1] + wa[0][2]*fv[n][2] + wa[0][3]*fv[n][3];
            acc[1][n] += wa[1][0]*fv[n][0] + wa[1][1]*fv[n][1] + wa[1][2]*fv[n][2] + wa[1][3]*fv[n][3];
            acc[2][n] += wa[2][0]*fv[n][0] + wa[2][1]*fv[n][1] + wa[2][2]*fv[n][2] + wa[2][3]*fv[n][3];
            acc[3][n] += wa[3][0]*fv[n][0] + wa[3][1]*fv[n][1] + wa[3][2]*fv[n][2] + wa[3][3]*fv[n][3];
        }

        #pragma unroll
        for (int a = 0; a < 4; ++a) wa[a] = wb[a];
    }

    // reduce across the 16 d-lanes, then atomic into o1
    #pragma unroll
    for (int a = 0; a < 4; ++a) {
        #pragma unroll
        for (int n = 0; n < 8; ++n) {
            float v = acc[a][n];
            v += __shfl_xor(v, 1);
            v += __shfl_xor(v, 2);
            v += __shfl_xor(v, 4);
            v += __shfl_xor(v, 8);
            if (dl == 0) atomicAdd(&o1[n * K1 + k0 + a], v);
        }
    }
}

// ---------------------------------------------------------------------------
// Kernel 5: FC2 (8x4096)@(4096x4096). One wave per output row; nt w-loads.
// ---------------------------------------------------------------------------
__global__ __launch_bounds__(256) void fc2_kernel(const float* __restrict__ w2,
                                                  const float* __restrict__ o1,
                                                  const float* __restrict__ b2,
                                                  float* __restrict__ o2) {
    int gw   = (blockIdx.x * 256 + threadIdx.x) >> 6;
    int lane = threadIdx.x & 63;
    if (gw >= K1) return;
    const float* wr = w2 + (size_t)gw * K1;
    const v4* fo = (const v4*)o1;
    float acc[8];
    #pragma unroll
    for (int n = 0; n < 8; ++n) acc[n] = 0.f;
    for (int itn = 0; itn < K1 / 256; ++itn) {   // 16
        v4 wv = ldnt4(wr + (itn * 64 + lane) * 4);
        #pragma unroll
        for (int n = 0; n < 8; ++n) {
            v4 f = fo[n * (K1/4) + itn * 64 + lane];
            acc[n] += wv[0]*f[0] + wv[1]*f[1] + wv[2]*f[2] + wv[3]*f[3];
        }
    }
    #pragma unroll
    for (int n = 0; n < 8; ++n) {
        float v = acc[n];
        #pragma unroll
        for (int m = 32; m >= 1; m >>= 1) v += __shfl_xor(v, m);
        if (lane == 0) o2[n * K1 + gw] = v + b2[gw];
    }
}

// ---------------------------------------------------------------------------
// Kernel 6: heads. k<81 -> wc/bc, else wl/bl. out (8,405) row-major.
// ---------------------------------------------------------------------------
__global__ __launch_bounds__(256) void fc3_kernel(const float* __restrict__ wc,
                                                  const float* __restrict__ bc,
                                                  const float* __restrict__ wl,
                                                  const float* __restrict__ bl,
                                                  const float* __restrict__ o2,
                                                  float* __restrict__ out) {
    int gw   = (blockIdx.x * 256 + threadIdx.x) >> 6;
    int lane = threadIdx.x & 63;
    if (gw >= 405) return;
    const float* wrow; float bias;
    if (gw < 81) { wrow = wc + (size_t)gw * K1;        bias = bc[gw]; }
    else         { wrow = wl + (size_t)(gw - 81) * K1; bias = bl[gw - 81]; }
    const v4* fo = (const v4*)o2;
    float acc[8];
    #pragma unroll
    for (int n = 0; n < 8; ++n) acc[n] = 0.f;
    for (int itn = 0; itn < K1 / 256; ++itn) {
        v4 wv = ldnt4(wrow + (itn * 64 + lane) * 4);
        #pragma unroll
        for (int n = 0; n < 8; ++n) {
            v4 f = fo[n * (K1/4) + itn * 64 + lane];
            acc[n] += wv[0]*f[0] + wv[1]*f[1] + wv[2]*f[2] + wv[3]*f[3];
        }
    }
    #pragma unroll
    for (int n = 0; n < 8; ++n) {
        float v = acc[n];
        #pragma unroll
        for (int m = 32; m >= 1; m >>= 1) v += __shfl_xor(v, m);
        if (lane == 0) out[n * 405 + gw] = v + bias;
    }
}

// ---------------------------------------------------------------------------
extern "C" void kernel_launch(void* const* d_in, const int* in_sizes, int n_in,
                              void* d_out, int out_size, void* d_ws, size_t ws_size,
                              hipStream_t stream) {
    const float* feat   = (const float*)d_in[0];
    const float* rois   = (const float*)d_in[1];
    const float* scores = (const float*)d_in[2];
    const float* w1     = (const float*)d_in[3];
    const float* b1     = (const float*)d_in[4];
    const float* w2     = (const float*)d_in[5];
    const float* b2     = (const float*)d_in[6];
    const float* wc     = (const float*)d_in[7];
    const float* bc     = (const float*)d_in[8];
    const float* wl     = (const float*)d_in[9];
    const float* bl     = (const float*)d_in[10];
    float* out = (float*)d_out;

    // workspace layout (floats): [0..255] roi ints, then pooled, o1, o2
    int*   roi_out = (int*)d_ws;
    float* pooled  = (float*)d_ws + 256;
    float* o1      = pooled + (size_t)NKEEP * D1;
    float* o2      = o1 + NKEEP * K1;

    nms_sel_kernel<<<1, 256, 0, stream>>>(rois, scores, roi_out);
    roi_pool_kernel<<<(NKEEP * D1 + 255) / 256, 256, 0, stream>>>(feat, roi_out, pooled);
    init_bias8_kernel<<<(NKEEP * K1 + 255) / 256, 256, 0, stream>>>(b1, o1, K1);
    fc1_kernel<<<64 * NSLICE, 256, 0, stream>>>(w1, pooled, o1);
    fc2_kernel<<<K1 / 4, 256, 0, stream>>>(w2, o1, b2, o2);
    fc3_kernel<<<(405 * 64 + 255) / 256, 256, 0, stream>>>(wc, bc, wl, bl, o2, out);
}